// Round 16
// baseline (1007.544 us; speedup 1.0000x reference)
//
#include <hip/hip_runtime.h>
#include <hip/hip_bf16.h>
#include <math.h>

// ---------- types ----------
typedef __attribute__((ext_vector_type(8))) short bf16x8;   // 8 bf16 in 4 VGPRs
typedef __attribute__((ext_vector_type(4))) float f32x4;

#define SCALE_QK 0.03608439182435162f   // 1/sqrt(768)

// ---------- helpers ----------
__device__ __forceinline__ unsigned short f2bf_rne(float f) {
    union { float f; unsigned u; } x; x.f = f;
    unsigned r = x.u + 0x7FFFu + ((x.u >> 16) & 1u);
    return (unsigned short)(r >> 16);
}
__device__ __forceinline__ void store4(unsigned short* p, float v0, float v1, float v2, float v3) {
    ushort4 o; o.x = f2bf_rne(v0); o.y = f2bf_rne(v1); o.z = f2bf_rne(v2); o.w = f2bf_rne(v3);
    *(ushort4*)p = o;
}
__device__ __forceinline__ void store4(float* p, float v0, float v1, float v2, float v3) {
    float4 o; o.x = v0; o.y = v1; o.z = v2; o.w = v3;
    *(float4*)p = o;
}
__device__ __forceinline__ void async_copy16(const void* g, void* l) {
    __builtin_amdgcn_global_load_lds(
        (const __attribute__((address_space(1))) void*)g,
        (__attribute__((address_space(3))) void*)l, 16, 0, 0);
}

// ---------- manual grid barrier, two-level (R16 = R15 with const s_sleep) ----------
// R14 post-mortem: single-counter barrier = 768 ACQ_REL RMWs + 768 spinning
// device-scope ACQUIRE loads on ONE cache line -> polls saturate the line,
// arrivals queue behind them: ~175 us/barrier x 4 = the 700 us regression.
// (Barrier CORRECTNESS proven: R14 passed -> co-residency + fences hold.)
// Fix: (1) arrivals spread over 8 padded group counters (<=96 RMWs/line,
// parallel); (2) last-in-group bumps a global counter (8 RMWs); (3) last
// group release-stores 8 PER-GROUP FLAG lines; (4) blocks poll only their
// group's flag — pure loads on RMW-free lines. s_sleep must be a LITERAL
// (R15 compile error) -> constant 32 (~2k cycles/poll).
// Region layout per phase (ints, stride 32 = 128 B padded):
//   [0..7]*32 group counters | 8*32 global | (9+g)*32 flags g=0..7
#define BAR_INTS_PER_PHASE (17 * 32)
__device__ __forceinline__ void gridbar(int* base, int b) {
    __syncthreads();                          // all block stores retired
    if (threadIdx.x == 0) {
        __threadfence();                      // release: write back this XCD's L2
        const int g = b & 7;
        int old = __hip_atomic_fetch_add(base + g * 32, 1,
                                         __ATOMIC_ACQ_REL, __HIP_MEMORY_SCOPE_AGENT);
        if (old == 95) {                      // last of 96 in group
            int go = __hip_atomic_fetch_add(base + 8 * 32, 1,
                                            __ATOMIC_ACQ_REL, __HIP_MEMORY_SCOPE_AGENT);
            if (go == 7) {                    // last group: broadcast 8 flag lines
#pragma unroll
                for (int i = 0; i < 8; ++i)
                    __hip_atomic_store(base + (9 + i) * 32, 1,
                                       __ATOMIC_RELEASE, __HIP_MEMORY_SCOPE_AGENT);
            }
        }
        while (__hip_atomic_load(base + (9 + g) * 32,
                                 __ATOMIC_ACQUIRE, __HIP_MEMORY_SCOPE_AGENT) == 0)
            __builtin_amdgcn_s_sleep(32);     // constant operand (ISA requirement)
        __threadfence();                      // acquire: invalidate stale cache
    }
    __syncthreads();
}

// ---------- shared 128x128 GEMM core (R0-proven 2-barrier loop) ----------
// R1-R3: every source-level async variant regressed; keep the 2-barrier loop.
// LDS XOR-swizzled 16B granules (conflict-free). MFMA operands swapped
// (D = B-frag x A-frag = C^T fragment) -> contiguous stores in epilogues.
__device__ __forceinline__ void gemm_core128(
    unsigned short* shA, unsigned short* shB,
    const unsigned short* __restrict__ A, int lda,
    const unsigned short* __restrict__ B, int ldb,
    long long tileM, long long tileN, int K,
    int t, int wm, int wn, int quad, int l16, f32x4 (&acc)[4][4])
{
    for (int k0 = 0; k0 < K; k0 += 64) {
        __syncthreads();
#pragma unroll
        for (int p = 0; p < 4; ++p) {
            const int g   = p * 256 + t;
            const int row = g >> 3;
            const int kg  = (g & 7) ^ (row & 7);
            async_copy16(A + (tileM + row) * (long long)lda + k0 + kg * 8, &shA[g << 3]);
            async_copy16(B + (tileN + row) * (long long)ldb + k0 + kg * 8, &shB[g << 3]);
        }
        __syncthreads();
#pragma unroll 1
        for (int h = 0; h < 2; ++h) {
            bf16x8 af[4], bfr[4];
#pragma unroll
            for (int mi = 0; mi < 4; ++mi) {
                const int row = wm + mi * 16 + l16;
                const int kg  = ((h << 2) | quad) ^ (row & 7);
                af[mi] = *(const bf16x8*)(&shA[row * 64 + kg * 8]);
            }
#pragma unroll
            for (int ni = 0; ni < 4; ++ni) {
                const int row = wn + ni * 16 + l16;
                const int kg  = ((h << 2) | quad) ^ (row & 7);
                bfr[ni] = *(const bf16x8*)(&shB[row * 64 + kg * 8]);
            }
#pragma unroll
            for (int mi = 0; mi < 4; ++mi)
#pragma unroll
                for (int ni = 0; ni < 4; ++ni)
                    acc[mi][ni] = __builtin_amdgcn_mfma_f32_16x16x32_bf16(
                        bfr[ni], af[mi], acc[mi][ni], 0, 0, 0);
        }
    }
}

// ================= phase bodies (verbatim R9-R12 math) =================

// ---- phase 1: prep (1212 virtual blocks) ----
__device__ __forceinline__ void prep_body(
    int blk, int t, unsigned short* sh,
    const float* __restrict__ w_qkv, const float* __restrict__ b_qkv,
    const float* __restrict__ w_out, const float* __restrict__ b_out,
    unsigned short* wqT, unsigned short* wkT, unsigned short* wvT,
    unsigned short* wob, float* v2f, float* bpp)
{
    __syncthreads();                                  // LDS reuse across virtual blocks
    if (blk < 432) {
        float (*shT)[65] = reinterpret_cast<float(*)[65]>(sh);   // 16640 B
        const int m  = blk / 144;
        const int r  = blk % 144;
        const int ty = r / 12;
        const int tx = r % 12;
        const float* W = w_qkv + (long long)m * 768 * 768;
        unsigned short* WT = (m == 0) ? wqT : (m == 1) ? wkT : wvT;
        const int il = t & 63;
        const int ob = t >> 6;
#pragma unroll
        for (int it = 0; it < 16; ++it) {
            const int ol = ob + it * 4;
            shT[ol][il] = W[(long long)(ty * 64 + ol) * 768 + tx * 64 + il];
        }
        __syncthreads();
#pragma unroll
        for (int it = 0; it < 16; ++it) {
            const int il2 = ob + it * 4;
            WT[(long long)(tx * 64 + il2) * 768 + ty * 64 + il] = f2bf_rne(shT[il][il2]);
        }
    } else if (blk < 624) {
        const int d = (blk - 432) * 4 + (t >> 6);
        const int l = t & 63;
        float s = 0.f;
        for (int o = l; o < 768; o += 64)
            s += w_out[(long long)d * 768 + o] * b_qkv[1536 + o];
        for (int off = 1; off < 64; off <<= 1) s += __shfl_xor(s, off);
        if (l == 0) bpp[d] = b_out[d] + s;
    } else if (blk < 636) {
        float* pvv = reinterpret_cast<float*>(reinterpret_cast<char*>(sh) + 16640); // 4x64
        const int i0   = (blk - 624) * 64;
        const int il   = t & 63;
        const int wave = t >> 6;
        const float* Wk = w_qkv + 768LL * 768;
        float a = 0.f;
        for (int o = wave * 192; o < wave * 192 + 192; ++o)
            a += Wk[(long long)o * 768 + i0 + il] * b_qkv[o];   // bq
        pvv[wave * 64 + il] = a;
        __syncthreads();
        if (t < 64) v2f[i0 + t] = pvv[t] + pvv[64 + t] + pvv[128 + t] + pvv[192 + t];
    } else {
        const int j = (blk - 636) * 256 + t;         // < 147456 exact
        float4 v = ((const float4*)w_out)[j];
        ushort4 o;
        o.x = f2bf_rne(v.x); o.y = f2bf_rne(v.y);
        o.z = f2bf_rne(v.z); o.w = f2bf_rne(v.w);
        ((ushort4*)wob)[j] = o;
    }
}

// ---- phase 2a: weight GEMMs (blocks 0..71): z=0: B2[0:768]=s*M^T ; z=1: W' ----
__device__ __forceinline__ void wgemm_body(
    int b, int t, unsigned short* sh,
    const unsigned short* wkT, const unsigned short* wqT,
    const unsigned short* wob, const unsigned short* wvT, unsigned short* B2)
{
    unsigned short* shA = sh;
    unsigned short* shB = sh + 8192;
    const int lane = t & 63;
    const int wave = t >> 6;
    const int wm   = (wave & 1) * 64;
    const int wn   = (wave >> 1) * 64;
    const int quad = lane >> 4;
    const int l16  = lane & 15;
    const int z  = b / 36;
    const int r  = b % 36;
    const long long tileM = (long long)(r / 6) * 128;
    const long long tileN = (long long)(r % 6) * 128;
    const unsigned short* A  = z ? wob : wkT;
    const unsigned short* Bp = z ? wvT : wqT;
    unsigned short* C = B2 + (long long)z * 768 * 768;
    const float sc = z ? 1.0f : SCALE_QK;   // bake QK scale into M

    f32x4 acc[4][4];
#pragma unroll
    for (int i = 0; i < 4; ++i)
#pragma unroll
        for (int j = 0; j < 4; ++j)
#pragma unroll
            for (int rr = 0; rr < 4; ++rr) acc[i][j][rr] = 0.0f;

    gemm_core128(shA, shB, A, 768, Bp, 768, tileM, tileN, 768, t, wm, wn, quad, l16, acc);

#pragma unroll
    for (int mi = 0; mi < 4; ++mi) {
        const long long gm = tileM + wm + mi * 16 + l16;
#pragma unroll
        for (int ni = 0; ni < 4; ++ni) {
            const long long gn0 = tileN + wn + ni * 16 + quad * 4;
            const f32x4 a = acc[mi][ni];
            store4(C + gm * 768 + gn0, a[0] * sc, a[1] * sc, a[2] * sc, a[3] * sc);
        }
    }
}

// ---- phase 2b: x convert + w dot (4096 units, 4 rows each) ----
__device__ __forceinline__ void cvtx_body(
    int u, int t,
    const float* __restrict__ x, unsigned short* xb,
    const float* __restrict__ v2f, float* wf)
{
    const int wave = t >> 6;
    const int lane = t & 63;
    const long long row = (long long)u * 4 + wave;
    const float4* xr = (const float4*)x + row * 192;
    ushort4* xbr = (ushort4*)xb + row * 192;
    const float4* v2 = (const float4*)v2f;
    float w = 0.f;
#pragma unroll
    for (int j = 0; j < 3; ++j) {
        const int c = j * 64 + lane;
        float4 v = xr[c];
        ushort4 o;
        o.x = f2bf_rne(v.x); o.y = f2bf_rne(v.y);
        o.z = f2bf_rne(v.z); o.w = f2bf_rne(v.w);
        xbr[c] = o;
        float4 b = v2[c];
        w += v.x * b.x + v.y * b.y + v.z * b.z + v.w * b.w;
    }
#pragma unroll
    for (int off = 1; off < 64; off <<= 1) w += __shfl_xor(w, off);
    if (lane == 0) wf[row] = w * SCALE_QK;
}

// ---- phase 3: x-GEMM tile (1536 tiles): xm cols 0..767, vwt transposed 768..1535 ----
__device__ __forceinline__ void xgemm_body(
    int tile, int t, unsigned short* sh,
    const unsigned short* xb, const unsigned short* B2,
    unsigned short* xm, unsigned short* vwt)
{
    unsigned short* shA = sh;
    unsigned short* shB = sh + 8448;
    const int lane = t & 63;
    const int wave = t >> 6;
    const int wm   = (wave & 1) * 64;
    const int wn   = (wave >> 1) * 64;
    const int quad = lane >> 4;
    const int l16  = lane & 15;
    const int bx = tile % 12;
    const int by = tile / 12;
    const long long tileM = (long long)by * 128;
    const long long tileN = (long long)bx * 128;

    f32x4 acc[4][4];
#pragma unroll
    for (int i = 0; i < 4; ++i)
#pragma unroll
        for (int j = 0; j < 4; ++j)
#pragma unroll
            for (int rr = 0; rr < 4; ++rr) acc[i][j][rr] = 0.0f;

    gemm_core128(shA, shB, xb, 768, B2, 768, tileM, tileN, 768, t, wm, wn, quad, l16, acc);

    const bool vt_block = (tileN >= 768);
    if (vt_block) __syncthreads();
    unsigned short* const shd = (wn == 0) ? shA : shB;   // pitch-132 d-major halves

#pragma unroll
    for (int mi = 0; mi < 4; ++mi) {
        const long long gm = tileM + wm + mi * 16 + l16;
#pragma unroll
        for (int ni = 0; ni < 4; ++ni) {
            const long long gn0 = tileN + wn + ni * 16 + quad * 4;
            const f32x4 a = acc[mi][ni];
            if (vt_block) {
                const int dl = (int)(ni * 16 + quad * 4);
                const int kl = wm + mi * 16 + l16;
                shd[(dl + 0) * 132 + kl] = f2bf_rne(a[0]);
                shd[(dl + 1) * 132 + kl] = f2bf_rne(a[1]);
                shd[(dl + 2) * 132 + kl] = f2bf_rne(a[2]);
                shd[(dl + 3) * 132 + kl] = f2bf_rne(a[3]);
            } else {
                store4(xm + gm * 768 + gn0, a[0], a[1], a[2], a[3]);
            }
        }
    }
    if (vt_block) {
        __syncthreads();
        const long long bvt  = tileM >> 10;
        const long long kin0 = tileM & 1023;
        const int dr = t >> 1;
        const int hf = t & 1;
        const unsigned short* src = (dr < 64) ? &shA[dr * 132] : &shB[(dr - 64) * 132];
        unsigned short* dst = vwt + (bvt * 768 + (tileN - 768) + dr) * 1024 + kin0 + hf * 64;
        src += hf * 64;
#pragma unroll
        for (int j = 0; j < 16; ++j)
            *(uint2*)(dst + j * 4) = *(const uint2*)(src + j * 4);
    }
}

// ---- phase 4: attn tile (1024 tiles, 128x128, R9-proven DO_EXP geometry) ----
// rpart slot (bx*2 + wn-half): 16 slots/row, each written exactly once (R8 lesson).
__device__ __forceinline__ void attn_body(
    int tile, int t, unsigned short* sh,
    const unsigned short* xm, const unsigned short* xb, unsigned short* att,
    const float* __restrict__ wf, float* rpart)
{
    unsigned short* shA = sh;
    unsigned short* shB = sh + 8192;
    const int lane = t & 63;
    const int wave = t >> 6;
    const int wm   = (wave & 1) * 64;
    const int wn   = (wave >> 1) * 64;
    const int quad = lane >> 4;
    const int l16  = lane & 15;
    const int bz = tile >> 6;          // tile = bz*64 + by*8 + bx
    const int by = (tile >> 3) & 7;
    const int bx = tile & 7;
    const unsigned short* A = xm + (long long)bz * 1024 * 768;
    const unsigned short* B = xb + (long long)bz * 1024 * 768;
    unsigned short* C = att + (long long)bz * 1024 * 1024;
    const long long tileM = (long long)by * 128;
    const long long tileN = (long long)bx * 128;

    f32x4 acc[4][4];
#pragma unroll
    for (int i = 0; i < 4; ++i)
#pragma unroll
        for (int j = 0; j < 4; ++j)
#pragma unroll
            for (int rr = 0; rr < 4; ++rr) acc[i][j][rr] = 0.0f;

    gemm_core128(shA, shB, A, 768, B, 768, tileM, tileN, 768, t, wm, wn, quad, l16, acc);

    const float* wfb = wf + (long long)bz * 1024;
    float wkv[4][4];
#pragma unroll
    for (int ni = 0; ni < 4; ++ni) {
        const long long gn0 = tileN + wn + ni * 16 + quad * 4;
        float4 t4 = *(const float4*)&wfb[gn0];
        wkv[ni][0] = t4.x; wkv[ni][1] = t4.y; wkv[ni][2] = t4.z; wkv[ni][3] = t4.w;
    }
#pragma unroll
    for (int mi = 0; mi < 4; ++mi) {
        const long long gm = tileM + wm + mi * 16 + l16;
        float rsum = 0.0f;
#pragma unroll
        for (int ni = 0; ni < 4; ++ni) {
            const long long gn0 = tileN + wn + ni * 16 + quad * 4;
            const f32x4 a = acc[mi][ni];
            const float v0 = __expf(a[0] + wkv[ni][0]);
            const float v1 = __expf(a[1] + wkv[ni][1]);
            const float v2 = __expf(a[2] + wkv[ni][2]);
            const float v3 = __expf(a[3] + wkv[ni][3]);
            rsum += (v0 + v1) + (v2 + v3);
            store4(C + gm * 1024 + gn0, v0, v1, v2, v3);
        }
        rsum += __shfl_xor(rsum, 16);
        rsum += __shfl_xor(rsum, 32);
        if (quad == 0) {
            const long long slot = (long long)(bx * 2 + (wn >> 6));
            rpart[(slot * 16 + bz) * 1024 + gm] = rsum;
        }
    }
}

// ---- phase 5: PV tile (768 tiles): out = (att @ vwt^T)/rowsum + b'' ----
__device__ __forceinline__ void pv_body(
    int tile, int t, unsigned short* sh,
    const unsigned short* att, const unsigned short* vwt, float* out,
    const float* __restrict__ bpp, const float* __restrict__ rpart)
{
    unsigned short* shA = sh;
    unsigned short* shB = sh + 8192;
    const int lane = t & 63;
    const int wave = t >> 6;
    const int wm   = (wave & 1) * 64;
    const int wn   = (wave >> 1) * 64;
    const int quad = lane >> 4;
    const int l16  = lane & 15;
    const int bx = tile % 6;           // d-tile
    const int rem = tile / 6;
    const int by = rem & 7;            // q-tile
    const int bz = rem >> 3;           // batch
    const unsigned short* A = att + (long long)bz * 1024 * 1024;
    const unsigned short* B = vwt + (long long)bz * 768 * 1024;
    float* C = out + (long long)bz * 1024 * 768;
    const long long tileM = (long long)by * 128;
    const long long tileN = (long long)bx * 128;

    f32x4 acc[4][4];
#pragma unroll
    for (int i = 0; i < 4; ++i)
#pragma unroll
        for (int j = 0; j < 4; ++j)
#pragma unroll
            for (int rr = 0; rr < 4; ++rr) acc[i][j][rr] = 0.0f;

    gemm_core128(shA, shB, A, 1024, B, 1024, tileM, tileN, 1024, t, wm, wn, quad, l16, acc);

#pragma unroll
    for (int mi = 0; mi < 4; ++mi) {
        const long long gm = tileM + wm + mi * 16 + l16;
        float s = 0.f;
#pragma unroll
        for (int j = 0; j < 16; ++j)
            s += rpart[((long long)j * 16 + bz) * 1024 + gm];
        const float w = 1.0f / s;
#pragma unroll
        for (int ni = 0; ni < 4; ++ni) {
            const long long gn0 = tileN + wn + ni * 16 + quad * 4;
            float4 bv = *(const float4*)&bpp[gn0];
            const f32x4 a = acc[mi][ni];
            store4(C + gm * 768 + gn0,
                   a[0] * w + bv.x, a[1] * w + bv.y, a[2] * w + bv.z, a[3] * w + bv.w);
        }
    }
}

// ================= mega kernel: 5 phases, one REGULAR launch =================
// R16 = R14 with the two-level barrier (R15 fixed: s_sleep literal). Single
// dispatch removes the ~10-13 us per-boundary overhead of the 5-launch chain.
// Co-residency by construction: __launch_bounds__(256,3) register cap +
// 33792 B LDS -> exactly 3 blocks/CU, 768 = 256 CUs x 3 all resident (R14
// proved this: passed correctly). Phase work XCD-chunked (b&7) for L2 locality.
__global__ __launch_bounds__(256, 3) void mega(
    const float* __restrict__ x, const float* __restrict__ w_qkv,
    const float* __restrict__ b_qkv, const float* __restrict__ w_out,
    const float* __restrict__ b_out, float* __restrict__ out,
    unsigned short* __restrict__ ws)
{
    __shared__ unsigned short sh[16896];   // 33792 B, carved per phase

    const int t = threadIdx.x;
    const int b = blockIdx.x;
    const int G = gridDim.x;               // 768
    const int x8 = b & 7;                  // XCD chunk id
    const int j8 = b >> 3;                 // index within chunk (0..95)
    const int C8 = G >> 3;                 // 96 blocks per chunk

    // workspace layout (matches launcher)
    const long long MS = 16384;
    unsigned short* xb  = ws;
    unsigned short* wob = xb  + MS * 768;
    unsigned short* wqT = wob + 768LL * 768;
    unsigned short* wkT = wqT + 768LL * 768;
    unsigned short* wvT = wkT + 768LL * 768;
    unsigned short* B2  = wvT + 768LL * 768;
    unsigned short* xm  = B2  + 1536LL * 768;
    unsigned short* vwt = xm  + MS * 768;
    unsigned short* att = vwt + 16LL * 768 * 1024;
    float* rpart = (float*)(att + 16LL * 1024 * 1024);   // [16][16][1024]
    float* v2f   = rpart + 16 * MS;
    float* bpp   = v2f + 768;
    float* wf    = bpp + 768;
    int*   bar   = (int*)(wf + MS);        // 4 x BAR_INTS_PER_PHASE (memset 0)

    // ---- phase 1: prep ----
    for (int vb = b; vb < 1212; vb += G)
        prep_body(vb, t, sh, w_qkv, b_qkv, w_out, b_out,
                  wqT, wkT, wvT, wob, v2f, bpp);
    gridbar(bar + 0 * BAR_INTS_PER_PHASE, b);

    // ---- phase 2: weight GEMMs (blocks 0..71) || x convert + w dot ----
    if (b < 72) {
        wgemm_body(b, t, sh, wkT, wqT, wob, wvT, B2);
    } else {
        for (int u = b - 72; u < 4096; u += G - 72)
            cvtx_body(u, t, x, xb, v2f, wf);
    }
    gridbar(bar + 1 * BAR_INTS_PER_PHASE, b);

    // ---- phase 3: x-GEMM, 1536 tiles XCD-chunked ----
    for (int k = 0;; ++k) {
        const int off = j8 + k * C8;
        if (off >= 192) break;
        xgemm_body(x8 * 192 + off, t, sh, xb, B2, xm, vwt);
    }
    gridbar(bar + 2 * BAR_INTS_PER_PHASE, b);

    // ---- phase 4: attn, 1024 tiles XCD-chunked ----
    for (int k = 0;; ++k) {
        const int off = j8 + k * C8;
        if (off >= 128) break;
        attn_body(x8 * 128 + off, t, sh, xm, xb, att, wf, rpart);
    }
    gridbar(bar + 3 * BAR_INTS_PER_PHASE, b);

    // ---- phase 5: PV, 768 tiles XCD-chunked ----
    for (int k = 0;; ++k) {
        const int off = j8 + k * C8;
        if (off >= 96) break;
        pv_body(x8 * 96 + off, t, sh, att, vwt, out, bpp, rpart);
    }
}

// ---------- launcher ----------
// R16 pipeline: memset(barrier region) + ONE regular 768-block launch.
// Math identical to R12 (attn 128x128 / 16 rpart slots).
extern "C" void kernel_launch(void* const* d_in, const int* in_sizes, int n_in,
                              void* d_out, int out_size, void* d_ws, size_t ws_size,
                              hipStream_t stream) {
    (void)in_sizes; (void)n_in; (void)out_size; (void)ws_size;

    const float* x     = (const float*)d_in[0];
    const float* w_qkv = (const float*)d_in[1];
    const float* b_qkv = (const float*)d_in[2];
    const float* w_out = (const float*)d_in[3];
    const float* b_out = (const float*)d_in[4];
    float* out = (float*)d_out;
    unsigned short* ws = (unsigned short*)d_ws;

    // barrier region lives after wf in the workspace (see mega's layout)
    const long long MS = 16384;
    unsigned short* xb  = ws;
    unsigned short* wob = xb  + MS * 768;
    unsigned short* B2  = wob + 4LL * 768 * 768;        // wob + wqT + wkT + wvT
    unsigned short* xm  = B2  + 1536LL * 768;
    unsigned short* vwt = xm  + MS * 768;
    unsigned short* att = vwt + 16LL * 768 * 1024;
    float* rpart = (float*)(att + 16LL * 1024 * 1024);
    float* wf    = rpart + 16 * MS + 768 + 768;
    int*   bar   = (int*)(wf + MS);

    (void)hipMemsetAsync(bar, 0, 4 * BAR_INTS_PER_PHASE * sizeof(int), stream);
    mega<<<768, 256, 0, stream>>>(x, w_qkv, b_qkv, w_out, b_out, out, ws);
}

// Round 17
// 248.487 us; speedup vs baseline: 4.0547x; 4.0547x over previous
//
#include <hip/hip_runtime.h>
#include <hip/hip_bf16.h>
#include <math.h>

// ---------- types ----------
typedef __attribute__((ext_vector_type(8))) short bf16x8;   // 8 bf16 in 4 VGPRs
typedef __attribute__((ext_vector_type(4))) float f32x4;

#define SCALE_QK 0.03608439182435162f   // 1/sqrt(768)

// ---------- helpers ----------
__device__ __forceinline__ unsigned short f2bf_rne(float f) {
    union { float f; unsigned u; } x; x.f = f;
    unsigned r = x.u + 0x7FFFu + ((x.u >> 16) & 1u);
    return (unsigned short)(r >> 16);
}

// 4 consecutive elements per lane (transposed-MFMA epilogue): 8B bf16 / 16B f32
__device__ __forceinline__ void store4(unsigned short* p, float v0, float v1, float v2, float v3) {
    ushort4 o; o.x = f2bf_rne(v0); o.y = f2bf_rne(v1); o.z = f2bf_rne(v2); o.w = f2bf_rne(v3);
    *(ushort4*)p = o;          // 8 B store, gn0 % 4 == 0 -> aligned
}
__device__ __forceinline__ void store4(float* p, float v0, float v1, float v2, float v3) {
    float4 o; o.x = v0; o.y = v1; o.z = v2; o.w = v3;
    *(float4*)p = o;           // 16 B store
}

__device__ __forceinline__ void async_copy16(const void* g, void* l) {
    __builtin_amdgcn_global_load_lds(
        (const __attribute__((address_space(1))) void*)g,
        (__attribute__((address_space(3))) void*)l, 16, 0, 0);
}

// ---------- shared 128x128 GEMM core (R0-proven 2-barrier loop) ----------
// R1-R3 post-mortems: every source-level async variant regressed (toolchain drains
// LDS-DMA at phase boundaries); keep the 2-barrier loop. DO NOT re-add pipelining.
// R13-R16 post-mortems: single-dispatch persistent kernel with grid barriers costs
// ~190 us/barrier (device-scope fence = L2 writeback + HBM refetch, structural);
// cooperative launch is rejected by the harness. DO NOT re-attempt mega-kernels.
// LDS XOR-swizzled 16B granules (SQ_LDS_BANK_CONFLICT=0). MFMA operands swapped
// (D = B-frag x A-frag = C^T fragment) -> contiguous stores in epilogues.
__device__ __forceinline__ void gemm_core128(
    unsigned short* shA, unsigned short* shB,
    const unsigned short* __restrict__ A, int lda,
    const unsigned short* __restrict__ B, int ldb,
    long long tileM, long long tileN, int K,
    int t, int wm, int wn, int quad, int l16, f32x4 (&acc)[4][4])
{
    for (int k0 = 0; k0 < K; k0 += 64) {
        __syncthreads();   // previous iter's frags consumed before overwrite
#pragma unroll
        for (int p = 0; p < 4; ++p) {
            const int g   = p * 256 + t;        // LDS granule 0..1023 (lane-ordered)
            const int row = g >> 3;             // 0..127
            const int kg  = (g & 7) ^ (row & 7);// swizzled source k-granule
            async_copy16(A + (tileM + row) * (long long)lda + k0 + kg * 8, &shA[g << 3]);
            async_copy16(B + (tileN + row) * (long long)ldb + k0 + kg * 8, &shB[g << 3]);
        }
        __syncthreads();   // compiler drains vmcnt(0) before barrier

#pragma unroll 1           // keep only one K-half's fragments live (VGPR cap)
        for (int h = 0; h < 2; ++h) {
            bf16x8 af[4], bfr[4];
#pragma unroll
            for (int mi = 0; mi < 4; ++mi) {
                const int row = wm + mi * 16 + l16;
                const int kg  = ((h << 2) | quad) ^ (row & 7);
                af[mi] = *(const bf16x8*)(&shA[row * 64 + kg * 8]);
            }
#pragma unroll
            for (int ni = 0; ni < 4; ++ni) {
                const int row = wn + ni * 16 + l16;
                const int kg  = ((h << 2) | quad) ^ (row & 7);
                bfr[ni] = *(const bf16x8*)(&shB[row * 64 + kg * 8]);
            }
#pragma unroll
            for (int mi = 0; mi < 4; ++mi)
#pragma unroll
                for (int ni = 0; ni < 4; ++ni)
                    acc[mi][ni] = __builtin_amdgcn_mfma_f32_16x16x32_bf16(
                        bfr[ni], af[mi], acc[mi][ni], 0, 0, 0);   // swapped: C^T frag
        }
    }
}

// ---------- prep: weight transposes + v2 direct + b'' + wob cvt (no atomics) ----------
// blocks 0..431:    64x64-tile transposes of Wq/Wk/Wv (fp32 [o][i] -> bf16 [i][o])
// blocks 432..623:  b''[d] = b_out[d] + sum_o Wout[d,o]*bv[o]   (wave per row)
// blocks 624..635:  v2[i] = sum_o Wk[o,i]*bq[o] directly (exactly-once writes)
// blocks 636..1211: w_out fp32 -> wob bf16 (flat, 576*256 = 147456 float4 exact)
__global__ __launch_bounds__(256) void prep(
    const float* __restrict__ w_qkv, const float* __restrict__ b_qkv,
    const float* __restrict__ w_out, const float* __restrict__ b_out,
    unsigned short* __restrict__ wqT, unsigned short* __restrict__ wkT,
    unsigned short* __restrict__ wvT, unsigned short* __restrict__ wob,
    float* __restrict__ v2f, float* __restrict__ bpp)
{
    const int blk = blockIdx.x;
    const int t   = threadIdx.x;
    if (blk < 432) {
        __shared__ float sh[64][65];     // +1 pad: conflict-free transpose
        const int m  = blk / 144;        // matrix 0=Wq 1=Wk 2=Wv
        const int r  = blk % 144;
        const int ty = r / 12;           // o-tile
        const int tx = r % 12;           // i-tile
        const float* W = w_qkv + (long long)m * 768 * 768;
        unsigned short* WT = (m == 0) ? wqT : (m == 1) ? wkT : wvT;
        const int il = t & 63;
        const int ob = t >> 6;
#pragma unroll
        for (int it = 0; it < 16; ++it) {
            const int ol = ob + it * 4;
            sh[ol][il] = W[(long long)(ty * 64 + ol) * 768 + tx * 64 + il];
        }
        __syncthreads();
#pragma unroll
        for (int it = 0; it < 16; ++it) {
            const int il2 = ob + it * 4;
            WT[(long long)(tx * 64 + il2) * 768 + ty * 64 + il] = f2bf_rne(sh[il][il2]);
        }
    } else if (blk < 624) {
        const int d = (blk - 432) * 4 + (t >> 6);
        const int l = t & 63;
        float s = 0.f;
        for (int o = l; o < 768; o += 64)
            s += w_out[(long long)d * 768 + o] * b_qkv[1536 + o];
        for (int off = 1; off < 64; off <<= 1) s += __shfl_xor(s, off);
        if (l == 0) bpp[d] = b_out[d] + s;
    } else if (blk < 636) {
        __shared__ float pvv[4][64];
        const int i0   = (blk - 624) * 64;
        const int il   = t & 63;
        const int wave = t >> 6;
        const float* Wk = w_qkv + 768LL * 768;
        float a = 0.f;
        for (int o = wave * 192; o < wave * 192 + 192; ++o)
            a += Wk[(long long)o * 768 + i0 + il] * b_qkv[o];   // bq
        pvv[wave][il] = a;
        __syncthreads();
        if (t < 64) v2f[i0 + t] = pvv[0][t] + pvv[1][t] + pvv[2][t] + pvv[3][t];
    } else {
        const int j = (blk - 636) * 256 + t;         // < 147456 exact
        float4 v = ((const float4*)w_out)[j];
        ushort4 o;
        o.x = f2bf_rne(v.x); o.y = f2bf_rne(v.y);
        o.z = f2bf_rne(v.z); o.w = f2bf_rne(v.w);
        ((ushort4*)wob)[j] = o;
    }
}

// ---------- wgemm_cvt: weight GEMMs (72 blocks) || x convert + w dot (4096 blocks) ----------
// blocks 0..71:   z=blk/36: z=0: B2[0:768] = s*M^T ; z=1: B2[768:1536] = W'
// blocks 72..4167: per wave one x row: xb = bf16(x), wf[row] = s * (x . v2)
__global__ __launch_bounds__(256) void wgemm_cvt(
    const unsigned short* __restrict__ wkT, const unsigned short* __restrict__ wqT,
    const unsigned short* __restrict__ wob, const unsigned short* __restrict__ wvT,
    unsigned short* __restrict__ B2,
    const float* __restrict__ x, unsigned short* __restrict__ xb,
    const float* __restrict__ v2f, float* __restrict__ wf)
{
    const int t = threadIdx.x;
    if (blockIdx.x < 72) {
        __shared__ unsigned short shA[8192];
        __shared__ unsigned short shB[8192];
        const int lane = t & 63;
        const int wave = t >> 6;
        const int wm   = (wave & 1) * 64;
        const int wn   = (wave >> 1) * 64;
        const int quad = lane >> 4;
        const int l16  = lane & 15;
        const int z  = blockIdx.x / 36;
        const int r  = blockIdx.x % 36;
        const long long tileM = (long long)(r / 6) * 128;
        const long long tileN = (long long)(r % 6) * 128;
        const unsigned short* A  = z ? wob : wkT;
        const unsigned short* Bp = z ? wvT : wqT;
        unsigned short* C = B2 + (long long)z * 768 * 768;
        const float sc = z ? 1.0f : SCALE_QK;   // bake QK scale into M

        f32x4 acc[4][4];
#pragma unroll
        for (int i = 0; i < 4; ++i)
#pragma unroll
            for (int j = 0; j < 4; ++j)
#pragma unroll
                for (int rr = 0; rr < 4; ++rr) acc[i][j][rr] = 0.0f;

        gemm_core128(shA, shB, A, 768, Bp, 768, tileM, tileN, 768,
                     t, wm, wn, quad, l16, acc);

#pragma unroll
        for (int mi = 0; mi < 4; ++mi) {
            const long long gm = tileM + wm + mi * 16 + l16;
#pragma unroll
            for (int ni = 0; ni < 4; ++ni) {
                const long long gn0 = tileN + wn + ni * 16 + quad * 4;
                const f32x4 a = acc[mi][ni];
                store4(C + gm * 768 + gn0, a[0] * sc, a[1] * sc, a[2] * sc, a[3] * sc);
            }
        }
    } else {
        const int wave = t >> 6;
        const int lane = t & 63;
        const long long row = (long long)(blockIdx.x - 72) * 4 + wave;  // 16384 exact
        const float4* xr = (const float4*)x + row * 192;
        ushort4* xbr = (ushort4*)xb + row * 192;
        const float4* v2 = (const float4*)v2f;
        float w = 0.f;
#pragma unroll
        for (int j = 0; j < 3; ++j) {
            const int c = j * 64 + lane;
            float4 v = xr[c];
            ushort4 o;
            o.x = f2bf_rne(v.x); o.y = f2bf_rne(v.y);
            o.z = f2bf_rne(v.z); o.w = f2bf_rne(v.w);
            xbr[c] = o;
            float4 b = v2[c];
            w += v.x * b.x + v.y * b.y + v.z * b.z + v.w * b.w;
        }
#pragma unroll
        for (int off = 1; off < 64; off <<= 1) w += __shfl_xor(w, off);
        if (lane == 0) wf[row] = w * SCALE_QK;
    }
}

// ---------- attn: att = exp(xm @ xb^T + w[k]), 128x256 tile ----------
// R12-proven: __launch_bounds__(256,2) caps allocator at 128 VGPR (+128 AGPR =
// 256 unified = 2 waves/SIMD); wf loaded per-ni in epilogue (no hoist).
// -> 2 blocks/CU, capacity 512 = grid = ONE round at 8 waves/CU.
// Row exp-sums -> rpart[bx*2 + k-half][row], 8 slots, each written exactly once.
__global__ __launch_bounds__(256, 2) void attn(
    const unsigned short* __restrict__ A, long long strideA,   // xm, lda=768
    const unsigned short* __restrict__ B, long long strideB,   // xb, ldb=768
    unsigned short* __restrict__ C, long long strideC,         // att, ldc=1024
    const float* __restrict__ wf, float* __restrict__ rpart)
{
    __shared__ unsigned short shA[128 * 64];   // 16 KB
    __shared__ unsigned short shB[256 * 64];   // 32 KB

    const int t    = threadIdx.x;
    const int lane = t & 63;
    const int wave = t >> 6;
    const int wm   = (wave & 1) * 64;    // q-half
    const int wk   = (wave >> 1);        // k-half (0/1 -> rows 0/128 of B-tile)
    const int quad = lane >> 4;
    const int l16  = lane & 15;

    // XCD-chunked swizzle (nwg = 512, %8 == 0)
    const int nwg  = 512;
    const int orig = blockIdx.x + 4 * (blockIdx.y + 8 * blockIdx.z);
    const int id   = (orig & 7) * (nwg >> 3) + (orig >> 3);
    const int bx   = id & 3;
    const int rem  = id >> 2;
    const int by   = rem & 7;
    const int bz   = rem >> 3;

    const long long batch = bz;
    A += batch * strideA;
    B += batch * strideB;
    C += batch * strideC;
    const long long tileM = (long long)by * 128;
    const long long tileN = (long long)bx * 256;

    f32x4 acc[4][8];
#pragma unroll
    for (int i = 0; i < 4; ++i)
#pragma unroll
        for (int j = 0; j < 8; ++j)
#pragma unroll
            for (int r = 0; r < 4; ++r) acc[i][j][r] = 0.0f;

    for (int k0 = 0; k0 < 768; k0 += 64) {
        __syncthreads();
#pragma unroll
        for (int p = 0; p < 4; ++p) {            // A-tile: 128 rows
            const int g   = p * 256 + t;
            const int row = g >> 3;
            const int kg  = (g & 7) ^ (row & 7);
            async_copy16(A + (tileM + row) * 768LL + k0 + kg * 8, &shA[g << 3]);
        }
#pragma unroll
        for (int p = 0; p < 8; ++p) {            // B-tile: 256 rows
            const int g   = p * 256 + t;
            const int row = g >> 3;
            const int kg  = (g & 7) ^ (row & 7);
            async_copy16(B + (tileN + row) * 768LL + k0 + kg * 8, &shB[g << 3]);
        }
        __syncthreads();

#pragma unroll 1
        for (int h = 0; h < 2; ++h) {
            bf16x8 af[4], bfr[8];
#pragma unroll
            for (int mi = 0; mi < 4; ++mi) {
                const int row = wm + mi * 16 + l16;
                const int kg  = ((h << 2) | quad) ^ (row & 7);
                af[mi] = *(const bf16x8*)(&shA[row * 64 + kg * 8]);
            }
#pragma unroll
            for (int ni = 0; ni < 8; ++ni) {
                const int row = wk * 128 + ni * 16 + l16;
                const int kg  = ((h << 2) | quad) ^ (row & 7);
                bfr[ni] = *(const bf16x8*)(&shB[row * 64 + kg * 8]);
            }
#pragma unroll
            for (int mi = 0; mi < 4; ++mi)
#pragma unroll
                for (int ni = 0; ni < 8; ++ni)
                    acc[mi][ni] = __builtin_amdgcn_mfma_f32_16x16x32_bf16(
                        bfr[ni], af[mi], acc[mi][ni], 0, 0, 0);   // swapped: C^T frag
        }
    }

    // epilogue: lane -> q = l16, k = quad*4 + {0..3} within each ni*16 block
    // wf loaded per-ni (no register hoist — R12 occupancy fix)
    const float* wfb = wf + batch * 1024;
#pragma unroll
    for (int mi = 0; mi < 4; ++mi) {
        const long long gm = tileM + wm + mi * 16 + l16;
        float rsum = 0.0f;
#pragma unroll
        for (int ni = 0; ni < 8; ++ni) {
            const long long gn0 = tileN + wk * 128 + ni * 16 + quad * 4;
            const float4 t4 = *(const float4*)&wfb[gn0];
            const f32x4 a = acc[mi][ni];
            const float v0 = __expf(a[0] + t4.x);
            const float v1 = __expf(a[1] + t4.y);
            const float v2 = __expf(a[2] + t4.z);
            const float v3 = __expf(a[3] + t4.w);
            rsum += (v0 + v1) + (v2 + v3);
            store4(C + gm * 1024 + gn0, v0, v1, v2, v3);
        }
        // lanes sharing l16 (quad bits = lane bits 4,5) hold disjoint k-ranges
        rsum += __shfl_xor(rsum, 16);
        rsum += __shfl_xor(rsum, 32);
        if (quad == 0) {   // slot (bx, k-half): written exactly once per (slot,row)
            const long long slot = (long long)(bx * 2 + wk);
            rpart[(slot * 16 + batch) * 1024 + gm] = rsum;
        }
    }
}

// ---------- NT bf16 GEMM: C[m,n] = f( scale * sum_k A[m,k]*B[n,k] ) + bias[n] ----------
// R0-proven structure (gemm_core128). XCD-chunked block swizzle kept.
//   DO_RSCALE: row m scaled by scale/sum_{j<8} rpart[j][row], plus bias (fp32).
//   DO_VT:     blocks with tileN in [768,1536) write vt[b][d][k] transposed via
//              LDS-staged coalesced path (R6).
template <typename OutT, bool DO_RSCALE, bool DO_VT>
__global__ __launch_bounds__(256) void gemm_nt_bf16(
    const unsigned short* __restrict__ A, int lda, long long strideA,
    const unsigned short* __restrict__ B, int ldb, long long strideB,
    OutT* __restrict__ C, int ldc, long long strideC,
    const float* __restrict__ bias, float scale, int K,
    const float* __restrict__ rscale, unsigned short* __restrict__ vtp)
{
    __shared__ unsigned short shA[DO_VT ? 8448 : 8192];
    __shared__ unsigned short shB[DO_VT ? 8448 : 8192];

    const int t    = threadIdx.x;
    const int lane = t & 63;
    const int wave = t >> 6;
    const int wm   = (wave & 1) * 64;
    const int wn   = (wave >> 1) * 64;
    const int quad = lane >> 4;
    const int l16  = lane & 15;

    // XCD-chunked block swizzle (all launch grids are %8 == 0)
    const int gx = gridDim.x, gy = gridDim.y;
    const int nwg = gx * gy * gridDim.z;
    const int orig = blockIdx.x + gx * (blockIdx.y + gy * blockIdx.z);
    const int id  = (orig & 7) * (nwg >> 3) + (orig >> 3);
    const int bx  = id % gx;
    const int rem = id / gx;
    const int by  = rem % gy;
    const int bz  = rem / gy;

    const long long batch = bz;
    A += batch * strideA;
    B += batch * strideB;
    C += batch * strideC;

    const long long tileM = (long long)by * 128;
    const long long tileN = (long long)bx * 128;
    const long long rowsPerBatch = (long long)gy * 128;

    f32x4 acc[4][4];
#pragma unroll
    for (int i = 0; i < 4; ++i)
#pragma unroll
        for (int j = 0; j < 4; ++j)
#pragma unroll
            for (int r = 0; r < 4; ++r) acc[i][j][r] = 0.0f;

    gemm_core128(shA, shB, A, lda, B, ldb, tileM, tileN, K, t, wm, wn, quad, l16, acc);

    // epilogue: D holds C^T tile: lane -> m = l16 (fixed row), n = quad*4 + {0..3}
    const bool vt_block = DO_VT && (tileN >= 768) && (tileN < 1536);
    if (vt_block) __syncthreads();
    unsigned short* const shd = (wn == 0) ? shA : shB;

#pragma unroll
    for (int mi = 0; mi < 4; ++mi) {
        const long long gm = tileM + wm + mi * 16 + l16;
        float w = scale;
        if (DO_RSCALE) {
            float s = 0.f;
#pragma unroll
            for (int j = 0; j < 8; ++j)
                s += rscale[((long long)j * gridDim.z + batch) * rowsPerBatch + gm];
            w = scale / s;
        }
#pragma unroll
        for (int ni = 0; ni < 4; ++ni) {
            const long long gn0 = tileN + wn + ni * 16 + quad * 4;
            float b0 = 0.f, b1 = 0.f, b2 = 0.f, b3 = 0.f;
            if (bias) {
                float4 bv = *(const float4*)&bias[gn0];
                b0 = bv.x; b1 = bv.y; b2 = bv.z; b3 = bv.w;
            }
            const f32x4 a = acc[mi][ni];
            const float v0 = a[0] * w + b0, v1 = a[1] * w + b1;
            const float v2 = a[2] * w + b2, v3 = a[3] * w + b3;
            if (vt_block) {
                const int dl = ni * 16 + quad * 4;
                const int kl = wm + mi * 16 + l16;
                shd[(dl + 0) * 132 + kl] = f2bf_rne(v0);
                shd[(dl + 1) * 132 + kl] = f2bf_rne(v1);
                shd[(dl + 2) * 132 + kl] = f2bf_rne(v2);
                shd[(dl + 3) * 132 + kl] = f2bf_rne(v3);
            } else {
                store4(C + gm * (long long)ldc + gn0, v0, v1, v2, v3);
            }
        }
    }
    if (vt_block) {
        __syncthreads();
        const long long bvt  = tileM >> 10;
        const long long kin0 = tileM & 1023;
        const int dr = t >> 1;
        const int hf = t & 1;
        const unsigned short* src = (dr < 64) ? &shA[dr * 132] : &shB[(dr - 64) * 132];
        unsigned short* dst = vtp + (bvt * 768 + (tileN - 768) + dr) * 1024 + kin0 + hf * 64;
        src += hf * 64;
#pragma unroll
        for (int j = 0; j < 16; ++j)
            *(uint2*)(dst + j * 4) = *(const uint2*)(src + j * 4);
    }
}

// ---------- launcher ----------
// R17 = R12 verbatim (best verified: 250.6 us). 5 launches:
//   att = exp(s*x M x^T + 1(s*w)^T),  out = (att @ (x W'^T)) / rowsum + b''
//   M = Wq^T Wk (scale baked), W' = Wout Wv, w = x(Wk^T bq), b'' = b_out + Wout bv.
extern "C" void kernel_launch(void* const* d_in, const int* in_sizes, int n_in,
                              void* d_out, int out_size, void* d_ws, size_t ws_size,
                              hipStream_t stream) {
    (void)in_sizes; (void)n_in; (void)out_size; (void)ws_size;

    const float* x     = (const float*)d_in[0];
    const float* w_qkv = (const float*)d_in[1];
    const float* b_qkv = (const float*)d_in[2];
    const float* w_out = (const float*)d_in[3];
    const float* b_out = (const float*)d_in[4];
    float* out = (float*)d_out;

    const int B = 16, S = 1024, D = 768;
    const long long MS = (long long)B * S;  // 16384 rows
    const int NB2 = 1536;                   // B2 rows: s*M^T (768) | W' (768)

    // workspace layout (bf16 = ushort), all 16B aligned
    unsigned short* xb  = (unsigned short*)d_ws;           // [16384][768]
    unsigned short* wob = xb  + MS * D;                    // [768][768]   Wout bf16
    unsigned short* wqT = wob + (long long)D * D;          // [768][768]   Wq^T bf16
    unsigned short* wkT = wqT + (long long)D * D;          // Wk^T
    unsigned short* wvT = wkT + (long long)D * D;          // Wv^T
    unsigned short* B2  = wvT + (long long)D * D;          // [1536][768]
    unsigned short* xm  = B2  + (long long)NB2 * D;        // [16384][768]  x(sM)^T
    unsigned short* vwt = xm  + MS * D;                    // [16][768][1024]  (x W'^T)^T
    unsigned short* att_ = vwt + (long long)B * D * S;     // [16][1024][1024] exp(logits)
    float* rpart = (float*)(att_ + (long long)B * S * S);  // [8][16][1024] exp-sum partials
    float* v2f   = rpart + 8 * MS;                         // [768]
    float* bpp   = v2f + D;                                // [768]  b''
    float* wf    = bpp + D;                                // [16384]

    // 1) prep: Wq^T/Wk^T/Wv^T transposes + v2 direct + b'' + wob cvt
    prep<<<1212, 256, 0, stream>>>(w_qkv, b_qkv, w_out, b_out,
                                   wqT, wkT, wvT, wob, v2f, bpp);

    // 2) merged: weight GEMMs (72 blocks, hidden) || x->bf16 + w = s*(x.v2)
    wgemm_cvt<<<4168, 256, 0, stream>>>(wkT, wqT, wob, wvT, B2, x, xb, v2f, wf);

    // 3) combined x-GEMM: [16384,1536] over B2
    //    cols 0..767 = x(sM) -> xm (compact ldc=768), 768..1535 -> vwt TRANSPOSED
    gemm_nt_bf16<unsigned short, false, true><<<dim3(NB2 / 128, (int)(MS / 128), 1), 256, 0, stream>>>(
        xb, D, 0, B2, D, 0, xm, D, 0, nullptr, 1.0f, D, nullptr, vwt);

    // 4) att = exp(xm @ xb^T + w[k]) per batch; 128x256 tiles, 512 blocks = 1 round
    attn<<<dim3(4, 8, B), 256, 0, stream>>>(
        xm, (long long)S * D, xb, (long long)S * D,
        att_, (long long)S * S, wf, rpart);

    // 5) out = (att @ vwt^T) / rowsum + b''   [16384,768] fp32 (final)
    gemm_nt_bf16<float, true, false><<<dim3(D / 128, S / 128, B), 256, 0, stream>>>(
        att_, S, (long long)S * S,
        vwt, S, (long long)D * S,
        out, D, (long long)S * D, bpp, 1.0f, S, rpart, nullptr);
}